// Round 12
// baseline (875.904 us; speedup 1.0000x reference)
//
#include <hip/hip_runtime.h>
#include <hip/hip_fp16.h>
#include <math.h>

// ---- problem constants ----
static constexpr int N_   = 10000;
static constexpr int E_   = 160000;
static constexpr int G_   = 64;
static constexpr int T_   = 5;
static constexpr int FIN_ = 75;
static constexpr int ED_  = 50;
static constexpr int FOUT_= 15;
static constexpr int TF_  = T_*FIN_;     // 375
static constexpr int AGGW_= 4*FIN_;      // 300
static constexpr int YC_  = 48;          // padded 45 -> 48 combined outputs
static constexpr int NP_  = 10112;       // padded node count = 158*64 (tile-exact)
static constexpr int AW_  = 400;         // Af row: 5 towers x 80 (f32)
static constexpr int BW_  = 384;         // Bh row: 5 towers x 76 + pad (fp16), 768 B
static constexpr int WK_  = 380;         // Wcomb K rows: 80 (h+pad) + 300 (agg fi-quad interleaved)

// ---- UAF ----
__device__ __forceinline__ float softplus_f(float x){
    return fmaxf(x, 0.f) + log1pf(expf(-fabsf(x)));
}
__device__ __forceinline__ float uaf_f(float v, const float* __restrict__ p){
    return softplus_f(p[0]*(v + p[1]) + p[2]*v*v) - softplus_f(p[3]*(v - p[1])) + p[4];
}
__device__ __forceinline__ unsigned pack2h(float a, float b){
    __half2 h = __floats2half2_rn(a, b);
    return *reinterpret_cast<unsigned*>(&h);
}

// ---- setup kernels ----
__global__ void k_h0(const int* __restrict__ x, const float* __restrict__ node_emb, float* __restrict__ hT){
    int i = blockIdx.x*blockDim.x + threadIdx.x;
    if (i >= 80*N_) return;
    int q = i / N_, n = i % N_;
    hT[(size_t)q*NP_ + n] = (q < FIN_) ? node_emb[x[n]*FIN_ + q] : 0.f;
}

__global__ void k_deg(const int* __restrict__ ei, int* __restrict__ deg_i){
    int e = blockIdx.x*blockDim.x + threadIdx.x;
    if (e >= E_) return;
    atomicAdd(&deg_i[ei[E_ + e]], 1);
}

__global__ void k_scan(const int* __restrict__ deg_i, int* __restrict__ offs, float* __restrict__ avglog){
    __shared__ int sd[1024];
    __shared__ float sf[1024];
    __shared__ int carry;
    if (threadIdx.x == 0) carry = 0;
    __syncthreads();
    float ls = 0.f;
    for (int base = 0; base < N_; base += 1024){
        int i = base + threadIdx.x;
        int v = (i < N_) ? deg_i[i] : 0;
        if (i < N_) ls += logf((float)v + 1.f);
        sd[threadIdx.x] = v;
        __syncthreads();
        for (int off = 1; off < 1024; off <<= 1){
            int t = (threadIdx.x >= off) ? sd[threadIdx.x - off] : 0;
            __syncthreads();
            sd[threadIdx.x] += t;
            __syncthreads();
        }
        if (i < N_) offs[i] = carry + sd[threadIdx.x] - v;
        __syncthreads();
        if (threadIdx.x == 0) carry += sd[1023];
        __syncthreads();
    }
    if (threadIdx.x == 0) offs[N_] = carry;
    sf[threadIdx.x] = ls;
    __syncthreads();
    for (int off = 512; off > 0; off >>= 1){
        if (threadIdx.x < off) sf[threadIdx.x] += sf[threadIdx.x + off];
        __syncthreads();
    }
    if (threadIdx.x == 0) avglog[0] = sf[0] / (float)N_;
}

__global__ void k_fill(const int* __restrict__ ei, const int* __restrict__ eattr,
                       const int* __restrict__ offs, int* __restrict__ cursor, int* __restrict__ csr){
    int e = blockIdx.x*blockDim.x + threadIdx.x;
    if (e >= E_) return;
    int d = ei[E_ + e];
    int pos = offs[d] + atomicAdd(&cursor[d], 1);
    csr[pos] = ei[e] | (eattr[e] << 16);
}

__global__ void k_amp(const int* __restrict__ deg_i, const float* __restrict__ avglog,
                      float* __restrict__ ampv, float* __restrict__ iampv){
    int n = blockIdx.x*blockDim.x + threadIdx.x;
    if (n >= N_) return;
    float dm = fmaxf((float)deg_i[n], 1.f);
    float a = logf(dm + 1.f) / avglog[0];
    ampv[n] = a;
    iampv[n] = 1.f / a;
}

__global__ void k_eemb(const float* __restrict__ edge_emb, const float* __restrict__ We,
                       const float* __restrict__ be, float* __restrict__ eembw){
    int i = blockIdx.x*blockDim.x + threadIdx.x;
    if (i >= 4*4*FIN_) return;
    int c = i % FIN_;
    int a = (i / FIN_) % 4;
    int l = i / (4*FIN_);
    float s = be[l*FIN_ + c];
    for (int k = 0; k < ED_; k++) s = fmaf(edge_emb[a*ED_ + k], We[(l*ED_ + k)*FIN_ + c], s);
    eembw[i] = s;
}

__global__ void k_tbl(const float* __restrict__ eembw, const float* __restrict__ Wpre,
                      const float* __restrict__ bpre, float* __restrict__ tbl){
    int i = blockIdx.x*blockDim.x + threadIdx.x;
    if (i >= 4*4*TF_) return;
    int f = i % FIN_;
    int t = (i / FIN_) % T_;
    int a = (i / TF_) % 4;
    int l = i / (4*TF_);
    float s = bpre[(l*T_ + t)*FIN_ + f];
    const float* em = eembw + (l*4 + a)*FIN_;
    const float* W3 = Wpre + ((size_t)(l*T_ + t)*225 + 2*FIN_)*FIN_;
    for (int c = 0; c < FIN_; c++) s = fmaf(em[c], W3[c*FIN_ + f], s);
    tbl[i] = s;
}

// Wcomb[l,t,c,j]: WK_=380 x 48 per (l,t). K rows: 0..74 h, 75..79 zero pad,
// c>=80: r=c-80, fi=r>>2, kind=r&3 -> src agg row kind*75+fi (matches fp16 quad order).
__global__ void k_wcomb(const float* __restrict__ Wpost, float* __restrict__ Wcomb){
    int i = blockIdx.x*blockDim.x + threadIdx.x;
    if (i >= 4*T_*WK_*YC_) return;
    int j = i % YC_;
    int c = (i / YC_) % WK_;
    int t = (i / (YC_*WK_)) % T_;
    int l = i / (YC_*WK_*T_);
    float v = 0.f;
    if (j < 45){
        int blk = j / 15, fo = j % 15;
        const float* Wp = Wpost + (size_t)(l*T_ + t)*975*15;
        if (c < FIN_){ if (blk == 0) v = Wp[c*15 + fo]; }
        else if (c >= 80){
            int r = c - 80;
            int fi = r >> 2, kind = r & 3;
            v = Wp[(FIN_ + blk*AGGW_ + kind*FIN_ + fi)*15 + fo];
        }
    }
    Wcomb[i] = v;
}

// zero-padded Wpre blocks: Wpre80[l*10+chunk][80][80], chunk=t*2+half
__global__ void k_wpre80(const float* __restrict__ Wpre, float* __restrict__ Wpre80){
    int i = blockIdx.x*blockDim.x + threadIdx.x;
    if (i >= 4*10*80*80) return;
    int c = i % 80;
    int r = (i / 80) % 80;
    int chunk = (i / 6400) % 10;
    int l = i / 64000;
    int t = chunk >> 1, half = chunk & 1;
    float v = 0.f;
    if (r < FIN_ && c < FIN_)
        v = Wpre[((size_t)(l*T_ + t)*225 + half*FIN_ + r)*FIN_ + c];
    Wpre80[i] = v;
}

// zero-padded Wlin: [l][75][80]
__global__ void k_wlin80(const float* __restrict__ Wlin, float* __restrict__ Wlin80){
    int i = blockIdx.x*blockDim.x + threadIdx.x;
    if (i >= 4*FIN_*80) return;
    int q = i % 80;
    int p = (i / 80) % FIN_;
    int l = i / (80*FIN_);
    Wlin80[i] = (q < FIN_) ? Wlin[(l*FIN_ + p)*FIN_ + q] : 0.f;
}

// ---- per-layer kernels ----
// k_post6-style pipelined GEMM for the A/B projections.
// M-tile 64, 128 threads, K=80 in 4 chunks of 20, double-buffered, reg prefetch.
// grid (158, 10); blockIdx.y = chunk = t*2+half. LDS-transposed coalesced stores.
__global__ void __launch_bounds__(128) k_A4(const float* __restrict__ hT, const float* __restrict__ Wpre80_l,
                                            float* __restrict__ Af, __half* __restrict__ Bh){
    __shared__ float smem[5760];      // 23.04 KB; Act[2][1280] @0, Wt[2][1600] @2560; Out[64][81] reuse
    float* ActB = smem;
    float* WtB  = smem + 2560;
    int chunkid = blockIdx.y;
    int t = chunkid >> 1, half = chunkid & 1;
    const float* __restrict__ Wl = Wpre80_l + (size_t)chunkid*6400;
    int n0 = blockIdx.x * 64;
    int tid = threadIdx.x;
    int tn = tid & 15, tj = tid >> 4;

    // prologue: stage K-chunk 0
    for (int i = tid; i < 320; i += 128){
        int r = i >> 4, c4 = i & 15;
        *(float4*)(&ActB[r*64 + c4*4]) = *(const float4*)(hT + (size_t)r*NP_ + n0 + c4*4);
    }
    for (int i = tid; i < 400; i += 128){
        int r = i / 20, c4 = i % 20;
        *(float4*)(&WtB[r*80 + c4*4]) = *(const float4*)(Wl + r*80 + c4*4);
    }
    __syncthreads();

    float acc[4][10];
    #pragma unroll
    for (int m = 0; m < 4; m++)
        #pragma unroll
        for (int j = 0; j < 10; j++) acc[m][j] = 0.f;

    float4 ph0, ph1, ph2, pw0, pw1, pw2, pw3;
    #pragma unroll 1
    for (int ch = 0; ch < 4; ch++){
        int buf = ch & 1;
        bool have = (ch + 1 < 4);
        if (have){
            const float* sp = hT + (size_t)((ch+1)*20)*NP_ + n0;
            { int i0 = tid;       ph0 = *(const float4*)(sp + (size_t)(i0 >> 4)*NP_ + (i0 & 15)*4); }
            { int i1 = tid + 128; ph1 = *(const float4*)(sp + (size_t)(i1 >> 4)*NP_ + (i1 & 15)*4); }
            if (tid < 64){ int i2 = tid + 256; ph2 = *(const float4*)(sp + (size_t)(i2 >> 4)*NP_ + (i2 & 15)*4); }
            const float* wp = Wl + (ch+1)*1600;
            { int i = tid;       pw0 = *(const float4*)(wp + (i/20)*80 + (i%20)*4); }
            { int i = tid + 128; pw1 = *(const float4*)(wp + (i/20)*80 + (i%20)*4); }
            { int i = tid + 256; pw2 = *(const float4*)(wp + (i/20)*80 + (i%20)*4); }
            if (tid < 16){ int i = tid + 384; pw3 = *(const float4*)(wp + (i/20)*80 + (i%20)*4); }
        }
        const float* A  = ActB + buf*1280;
        const float* Wb = WtB + buf*1600;
        #pragma unroll
        for (int k = 0; k < 20; k++){
            float4 av = *(const float4*)(A + (k<<6) + (tn<<2));
            const float2* wr = (const float2*)(Wb + k*80 + tj*10);
            float wv[10];
            #pragma unroll
            for (int j2 = 0; j2 < 5; j2++){ float2 w2 = wr[j2]; wv[2*j2] = w2.x; wv[2*j2+1] = w2.y; }
            #pragma unroll
            for (int j = 0; j < 10; j++){
                acc[0][j] = fmaf(av.x, wv[j], acc[0][j]);
                acc[1][j] = fmaf(av.y, wv[j], acc[1][j]);
                acc[2][j] = fmaf(av.z, wv[j], acc[2][j]);
                acc[3][j] = fmaf(av.w, wv[j], acc[3][j]);
            }
        }
        if (have){
            float* Ad = ActB + (buf ^ 1)*1280;
            float* Wd = WtB + (buf ^ 1)*1600;
            { int i0 = tid;       *(float4*)(&Ad[(i0 >> 4)*64 + (i0 & 15)*4]) = ph0; }
            { int i1 = tid + 128; *(float4*)(&Ad[(i1 >> 4)*64 + (i1 & 15)*4]) = ph1; }
            if (tid < 64){ int i2 = tid + 256; *(float4*)(&Ad[(i2 >> 4)*64 + (i2 & 15)*4]) = ph2; }
            { int i = tid;       *(float4*)(&Wd[(i/20)*80 + (i%20)*4]) = pw0; }
            { int i = tid + 128; *(float4*)(&Wd[(i/20)*80 + (i%20)*4]) = pw1; }
            { int i = tid + 256; *(float4*)(&Wd[(i/20)*80 + (i%20)*4]) = pw2; }
            if (tid < 16){ int i = tid + 384; *(float4*)(&Wd[(i/20)*80 + (i%20)*4]) = pw3; }
            __syncthreads();
        }
    }
    __syncthreads();   // stage buffers dead; reuse as Out[64][81]
    float* Out = smem;
    #pragma unroll
    for (int m = 0; m < 4; m++)
        #pragma unroll
        for (int j = 0; j < 10; j++)
            Out[(tn*4 + m)*81 + tj*10 + j] = acc[m][j];
    __syncthreads();
    if (half == 0){
        for (int i = tid; i < 64*20; i += 128){
            int node = i / 20, q4 = i % 20;
            int gn = n0 + node;
            if (gn < N_){
                const float* src = Out + node*81 + q4*4;
                *(float4*)(Af + (size_t)gn*AW_ + t*80 + q4*4) = make_float4(src[0], src[1], src[2], src[3]);
            }
        }
    } else {
        for (int i = tid; i < 64*38; i += 128){
            int node = i / 38, q = i % 38;
            int gn = n0 + node;
            if (gn < N_){
                const float* src = Out + node*81 + 2*q;
                *(unsigned*)((__half*)Bh + (size_t)gn*BW_ + t*76 + 2*q) = pack2h(src[0], src[1]);
            }
        }
    }
}

// per-node CSR aggregation -> packed fp16 quad {mean,mn,mx,sd} at agg2h[(t*75+fi)*NP_ + n]
__global__ void __launch_bounds__(128) k_agg(const float* __restrict__ Af, const __half* __restrict__ Bh,
                                             const int* __restrict__ offs, const int* __restrict__ csr,
                                             const float* __restrict__ tbl_l, uint2* __restrict__ agg2h){
    __shared__ float tl[4*TF_];
    int bid = blockIdx.x;
    int n = (bid & 7)*1250 + (bid >> 3);   // XCD swizzle
    for (int idx = threadIdx.x; idx < 4*TF_; idx += 128) tl[idx] = tbl_l[idx];
    __syncthreads();
    int s = offs[n], e_end = offs[n+1];
    int f0 = threadIdx.x;
    int f1 = threadIdx.x + 128;
    int f2r = threadIdx.x + 256;
    int f2 = (f2r < TF_) ? f2r : 0;
    int aoA0 = (f0/FIN_)*80 + f0%FIN_;
    int aoA1 = (f1/FIN_)*80 + f1%FIN_;
    int aoA2 = (f2/FIN_)*80 + f2%FIN_;
    int aoB0 = (f0/FIN_)*76 + f0%FIN_;
    int aoB1 = (f1/FIN_)*76 + f1%FIN_;
    int aoB2 = (f2/FIN_)*76 + f2%FIN_;
    const float* An = Af + (size_t)n*AW_;
    float a0 = An[aoA0], a1 = An[aoA1], a2 = An[aoA2];
    float s0=0.f,s1=0.f,s2=0.f, q0=0.f,q1=0.f,q2=0.f;
    float mn0=INFINITY,mn1=INFINITY,mn2=INFINITY;
    float mx0=-INFINITY,mx1=-INFINITY,mx2=-INFINITY;
    int e = s;
    for (; e + 3 < e_end; e += 4){
        float b0[4], b1[4], b2[4];
        const float* tt[4];
        #pragma unroll
        for (int u = 0; u < 4; u++){
            int pk = csr[e + u];
            const __half* B = Bh + (size_t)(pk & 0xFFFF)*BW_;
            tt[u] = tl + (pk >> 16)*TF_;
            b0[u] = __half2float(B[aoB0]);
            b1[u] = __half2float(B[aoB1]);
            b2[u] = __half2float(B[aoB2]);
        }
        #pragma unroll
        for (int u = 0; u < 4; u++){
            float m0 = a0 + b0[u] + tt[u][f0];
            float m1 = a1 + b1[u] + tt[u][f1];
            float m2 = a2 + b2[u] + tt[u][f2];
            s0 += m0; s1 += m1; s2 += m2;
            q0 = fmaf(m0,m0,q0); q1 = fmaf(m1,m1,q1); q2 = fmaf(m2,m2,q2);
            mn0 = fminf(mn0,m0); mx0 = fmaxf(mx0,m0);
            mn1 = fminf(mn1,m1); mx1 = fmaxf(mx1,m1);
            mn2 = fminf(mn2,m2); mx2 = fmaxf(mx2,m2);
        }
    }
    for (; e < e_end; e++){
        int pk = csr[e];
        const __half* B = Bh + (size_t)(pk & 0xFFFF)*BW_;
        const float* t0 = tl + (pk >> 16)*TF_;
        float m0 = a0 + __half2float(B[aoB0]) + t0[f0];
        float m1 = a1 + __half2float(B[aoB1]) + t0[f1];
        float m2 = a2 + __half2float(B[aoB2]) + t0[f2];
        s0 += m0; q0 = fmaf(m0,m0,q0); mn0 = fminf(mn0,m0); mx0 = fmaxf(mx0,m0);
        s1 += m1; q1 = fmaf(m1,m1,q1); mn1 = fminf(mn1,m1); mx1 = fmaxf(mx1,m1);
        s2 += m2; q2 = fmaf(m2,m2,q2); mn2 = fminf(mn2,m2); mx2 = fmaxf(mx2,m2);
    }
    float deg = (float)(e_end - s);
    float dc = fmaxf(deg, 1.f);
    float inv = 1.f / dc;
    bool empty = (deg == 0.f);
    {
        float mean = s0*inv;
        float sd = sqrtf(fmaxf(q0*inv - mean*mean, 0.f) + 1e-5f);
        int t = f0/FIN_, fi = f0%FIN_;
        uint2 o; o.x = pack2h(mean, empty?0.f:mn0); o.y = pack2h(empty?0.f:mx0, sd);
        agg2h[(size_t)(t*FIN_+fi)*NP_ + n] = o;
    }
    {
        float mean = s1*inv;
        float sd = sqrtf(fmaxf(q1*inv - mean*mean, 0.f) + 1e-5f);
        int t = f1/FIN_, fi = f1%FIN_;
        uint2 o; o.x = pack2h(mean, empty?0.f:mn1); o.y = pack2h(empty?0.f:mx1, sd);
        agg2h[(size_t)(t*FIN_+fi)*NP_ + n] = o;
    }
    if (f2r < TF_){
        float mean = s2*inv;
        float sd = sqrtf(fmaxf(q2*inv - mean*mean, 0.f) + 1e-5f);
        int t = f2r/FIN_, fi = f2r%FIN_;
        uint2 o; o.x = pack2h(mean, empty?0.f:mn2); o.y = pack2h(empty?0.f:mx2, sd);
        agg2h[(size_t)(t*FIN_+fi)*NP_ + n] = o;
    }
}

__device__ __forceinline__ void unp4_64(float* Ad, int i, uint2 u){
    int fq = i >> 6, n = i & 63;
    __half2 lo = *reinterpret_cast<__half2*>(&u.x);
    __half2 hi = *reinterpret_cast<__half2*>(&u.y);
    Ad[(fq*4+0)*64 + n] = __low2float(lo);
    Ad[(fq*4+1)*64 + n] = __high2float(lo);
    Ad[(fq*4+2)*64 + n] = __low2float(hi);
    Ad[(fq*4+3)*64 + n] = __high2float(hi);
}

// K-split double-buffered GEMM. M-tile 64, 128 threads (2 waves), grid (158, T, 2).
__global__ void __launch_bounds__(128) k_post6(const float* __restrict__ hT, const uint2* __restrict__ agg2h,
                                               const float* __restrict__ Wcomb_l,
                                               float* __restrict__ Yp0, float* __restrict__ Yp1){
    __shared__ float Act[2][20*64];
    __shared__ float Wt[2][20*YC_];
    int t = blockIdx.y;
    int kz = blockIdx.z;
    int c0 = kz ? 9 : 0;
    int c1 = kz ? 19 : 9;
    float* __restrict__ Yp = kz ? Yp1 : Yp0;
    int n0 = blockIdx.x * 64;
    int tid = threadIdx.x;
    int tn = tid & 15, tj = tid >> 4;
    const float* __restrict__ Wl = Wcomb_l + (size_t)t*WK_*YC_;
    const uint2* __restrict__ agt = agg2h + (size_t)t*FIN_*NP_;

    if (c0 < 4){
        const float* sp = hT + (size_t)(c0*20)*NP_ + n0;
        for (int i = tid; i < 320; i += 128){
            int r = i >> 4, c4 = i & 15;
            *(float4*)(&Act[0][r*64 + c4*4]) = *(const float4*)(sp + (size_t)r*NP_ + c4*4);
        }
    } else {
        const uint2* sp = agt + (size_t)((c0 - 4)*5)*NP_ + n0;
        for (int i = tid; i < 320; i += 128)
            unp4_64(Act[0], i, sp[(size_t)(i >> 6)*NP_ + (i & 63)]);
    }
    for (int i = tid; i < 240; i += 128){
        int r = i / 12, c4 = i % 12;
        *(float4*)(&Wt[0][r*YC_ + c4*4]) = *(const float4*)(Wl + (size_t)(c0*20 + r)*YC_ + c4*4);
    }
    __syncthreads();

    float acc[4][6];
    #pragma unroll
    for (int m = 0; m < 4; m++)
        #pragma unroll
        for (int j = 0; j < 6; j++) acc[m][j] = 0.f;

    float4 ph0, ph1, ph2, pw0, pw1;
    uint2  pb0, pb1, pb2;
    #pragma unroll 1
    for (int ch = c0; ch < c1; ch++){
        int buf = (ch - c0) & 1;
        int ch1 = ch + 1;
        bool have = (ch1 < c1);
        bool nh = (ch1 < 4);
        if (have){
            if (nh){
                const float* sp = hT + (size_t)(ch1*20)*NP_ + n0;
                { int i0 = tid;       ph0 = *(const float4*)(sp + (size_t)(i0 >> 4)*NP_ + (i0 & 15)*4); }
                { int i1 = tid + 128; ph1 = *(const float4*)(sp + (size_t)(i1 >> 4)*NP_ + (i1 & 15)*4); }
                if (tid < 64){ int i2 = tid + 256; ph2 = *(const float4*)(sp + (size_t)(i2 >> 4)*NP_ + (i2 & 15)*4); }
            } else {
                const uint2* sp = agt + (size_t)((ch1 - 4)*5)*NP_ + n0;
                { int i0 = tid;       pb0 = sp[(size_t)(i0 >> 6)*NP_ + (i0 & 63)]; }
                { int i1 = tid + 128; pb1 = sp[(size_t)(i1 >> 6)*NP_ + (i1 & 63)]; }
                if (tid < 64){ int i2 = tid + 256; pb2 = sp[(size_t)(i2 >> 6)*NP_ + (i2 & 63)]; }
            }
            { int i = tid; int r = i / 12, c4 = i % 12;
              pw0 = *(const float4*)(Wl + (size_t)(ch1*20 + r)*YC_ + c4*4); }
            if (tid < 112){ int i = tid + 128; int r = i / 12, c4 = i % 12;
              pw1 = *(const float4*)(Wl + (size_t)(ch1*20 + r)*YC_ + c4*4); }
        }
        const float* A = Act[buf];
        const float* Wb = Wt[buf];
        #pragma unroll
        for (int k = 0; k < 20; k++){
            float4 av = *(const float4*)(A + (k<<6) + (tn<<2));
            const float* wr = Wb + k*YC_ + tj*6;
            #pragma unroll
            for (int j = 0; j < 6; j++){
                float wv = wr[j];
                acc[0][j] = fmaf(av.x, wv, acc[0][j]);
                acc[1][j] = fmaf(av.y, wv, acc[1][j]);
                acc[2][j] = fmaf(av.z, wv, acc[2][j]);
                acc[3][j] = fmaf(av.w, wv, acc[3][j]);
            }
        }
        if (have){
            float* Ad = Act[buf ^ 1];
            float* Wd = Wt[buf ^ 1];
            if (nh){
                { int i0 = tid;       *(float4*)(&Ad[(i0 >> 4)*64 + (i0 & 15)*4]) = ph0; }
                { int i1 = tid + 128; *(float4*)(&Ad[(i1 >> 4)*64 + (i1 & 15)*4]) = ph1; }
                if (tid < 64){ int i2 = tid + 256; *(float4*)(&Ad[(i2 >> 4)*64 + (i2 & 15)*4]) = ph2; }
            } else {
                unp4_64(Ad, tid, pb0);
                unp4_64(Ad, tid + 128, pb1);
                if (tid < 64) unp4_64(Ad, tid + 256, pb2);
            }
            { int i = tid; int r = i / 12, c4 = i % 12; *(float4*)(&Wd[r*YC_ + c4*4]) = pw0; }
            if (tid < 112){ int i = tid + 128; int r = i / 12, c4 = i % 12; *(float4*)(&Wd[r*YC_ + c4*4]) = pw1; }
            __syncthreads();
        }
    }
    int nodeb = n0 + tn*4;
    #pragma unroll
    for (int j = 0; j < 6; j++){
        int col = t*YC_ + tj*6 + j;
        float4 v = make_float4(acc[0][j], acc[1][j], acc[2][j], acc[3][j]);
        if (nodeb + 3 < N_){
            *(float4*)(Yp + (size_t)col*NP_ + nodeb) = v;
        } else {
            #pragma unroll
            for (int m = 0; m < 4; m++)
                if (nodeb + m < N_) Yp[(size_t)col*NP_ + nodeb + m] = (&v.x)[m];
        }
    }
}

// combine (Yp0+Yp1) + Wlin + BN stats; q-range split over blockIdx.y
__global__ void __launch_bounds__(64) k_Y(const float* __restrict__ Yp0, const float* __restrict__ Yp1,
                                          const float* __restrict__ ampv,
                                          const float* __restrict__ iampv, const float* __restrict__ bpost_l,
                                          const float* __restrict__ Wlin80_l, const float* __restrict__ blin_l,
                                          float* __restrict__ olinT, float* __restrict__ bnsum, float* __restrict__ bnsq){
    __shared__ float st[64*77];
    int qbase = blockIdx.y * 40;
    int qcnt  = blockIdx.y ? 35 : 40;
    int n = blockIdx.x*64 + threadIdx.x;
    int nn = (n < N_) ? n : N_-1;
    bool valid = (n < N_);
    float amp = ampv[nn], iamp = iampv[nn];
    #pragma unroll 1
    for (int t = 0; t < T_; t++){
        #pragma unroll
        for (int fo = 0; fo < FOUT_; fo++){
            size_t b0 = (size_t)(t*YC_ + fo)*NP_ + nn;
            size_t b1 = (size_t)(t*YC_ + 15 + fo)*NP_ + nn;
            size_t b2 = (size_t)(t*YC_ + 30 + fo)*NP_ + nn;
            float v = (Yp0[b0] + Yp1[b0])
                    + amp  * (Yp0[b1] + Yp1[b1])
                    + iamp * (Yp0[b2] + Yp1[b2])
                    + bpost_l[t*FOUT_ + fo];
            st[threadIdx.x*77 + t*FOUT_ + fo] = v;
        }
    }
    __syncthreads();
    float acc[40];
    #pragma unroll
    for (int k = 0; k < 40; k++) acc[k] = (qbase + k < FIN_) ? blin_l[qbase + k] : 0.f;
    #pragma unroll 1
    for (int p = 0; p < FIN_; p++){
        float yv = st[threadIdx.x*77 + p];
        const float* Wp = Wlin80_l + p*80 + qbase;
        #pragma unroll
        for (int k = 0; k < 40; k++) acc[k] = fmaf(yv, Wp[k], acc[k]);
    }
    if (valid){
        #pragma unroll
        for (int k = 0; k < 40; k++){
            int q = qbase + k;
            if (q < FIN_) olinT[(size_t)q*NP_ + n] = acc[k];
        }
    }
    __syncthreads();
    #pragma unroll
    for (int k = 0; k < 40; k++) st[threadIdx.x*77 + k] = valid ? acc[k] : 0.f;
    __syncthreads();
    for (int qq = threadIdx.x; qq < qcnt; qq += 64){
        float s = 0.f, s2 = 0.f;
        #pragma unroll 4
        for (int m = 0; m < 64; m++){ float v = st[m*77 + qq]; s += v; s2 = fmaf(v, v, s2); }
        atomicAdd(&bnsum[qbase + qq], s);
        atomicAdd(&bnsq[qbase + qq], s2);
    }
}

__global__ void k_bn(const float* __restrict__ olinT, const float* __restrict__ bnsum, const float* __restrict__ bnsq,
                     const float* __restrict__ gamma_l, const float* __restrict__ beta_l,
                     const float* __restrict__ uafp, float* __restrict__ hT){
    int i = blockIdx.x*blockDim.x + threadIdx.x;
    if (i >= FIN_*N_) return;
    int q = i / N_, n = i % N_;
    float mu = bnsum[q] * (1.f/(float)N_);
    float var = bnsq[q] * (1.f/(float)N_) - mu*mu;
    float xh = (olinT[(size_t)q*NP_ + n] - mu) * rsqrtf(var + 1e-5f) * gamma_l[q] + beta_l[q];
    hT[(size_t)q*NP_ + n] = uaf_f(xh, uafp);
}

// ---- pooling + MLP ----
__global__ void __launch_bounds__(256) k_pool2(const float* __restrict__ hT, const int* __restrict__ batch,
                                               float* __restrict__ pooled){
    __shared__ int sb[2];
    int g = blockIdx.x;
    if (threadIdx.x < 2){
        int key = g + threadIdx.x;
        int lo = 0, hi = N_;
        while (lo < hi){ int mid = (lo + hi) >> 1; if (batch[mid] < key) lo = mid + 1; else hi = mid; }
        sb[threadIdx.x] = lo;
    }
    __syncthreads();
    int s = sb[0], e = sb[1];
    int wave = threadIdx.x >> 6, lane = threadIdx.x & 63;
    for (int q = wave; q < FIN_; q += 4){
        float sum = 0.f;
        for (int n = s + lane; n < e; n += 64) sum += hT[(size_t)q*NP_ + n];
        #pragma unroll
        for (int off = 32; off > 0; off >>= 1) sum += __shfl_down(sum, off);
        if (lane == 0) pooled[g*FIN_ + q] = sum;
    }
}

__global__ void __launch_bounds__(64) k_mlp(const float* __restrict__ pooled,
        const float* __restrict__ mW1, const float* __restrict__ mb1,
        const float* __restrict__ mW2, const float* __restrict__ mb2,
        const float* __restrict__ mW3, const float* __restrict__ mb3,
        const float* __restrict__ uafp, float* __restrict__ outp){
    __shared__ float pr[FIN_];
    __shared__ float z1[50];
    __shared__ float z2[25];
    int g = blockIdx.x;
    for (int c = threadIdx.x; c < FIN_; c += 64) pr[c] = pooled[g*FIN_ + c];
    __syncthreads();
    if (threadIdx.x < 50){
        float s = mb1[threadIdx.x];
        for (int c = 0; c < FIN_; c++) s = fmaf(pr[c], mW1[c*50 + threadIdx.x], s);
        z1[threadIdx.x] = uaf_f(s, uafp);
    }
    __syncthreads();
    if (threadIdx.x < 25){
        float s = mb2[threadIdx.x];
        for (int c = 0; c < 50; c++) s = fmaf(z1[c], mW2[c*25 + threadIdx.x], s);
        z2[threadIdx.x] = uaf_f(s, uafp);
    }
    __syncthreads();
    if (threadIdx.x == 0){
        float s = mb3[0];
        for (int c = 0; c < 25; c++) s = fmaf(z2[c], mW3[c], s);
        outp[g] = s;
    }
}

extern "C" void kernel_launch(void* const* d_in, const int* in_sizes, int n_in,
                              void* d_out, int out_size, void* d_ws, size_t ws_size,
                              hipStream_t stream) {
    const int* x         = (const int*)d_in[0];
    const int* ei        = (const int*)d_in[1];
    const int* eattr     = (const int*)d_in[2];
    const int* batch     = (const int*)d_in[3];
    const float* node_emb= (const float*)d_in[4];
    const float* edge_emb= (const float*)d_in[5];
    const float* We      = (const float*)d_in[6];
    const float* be      = (const float*)d_in[7];
    const float* Wpre    = (const float*)d_in[8];
    const float* bpre    = (const float*)d_in[9];
    const float* Wpost   = (const float*)d_in[10];
    const float* bpost   = (const float*)d_in[11];
    const float* Wlin    = (const float*)d_in[12];
    const float* blin    = (const float*)d_in[13];
    const float* bn_gamma= (const float*)d_in[14];
    const float* bn_beta = (const float*)d_in[15];
    const float* uafp    = (const float*)d_in[16];
    const float* mW1     = (const float*)d_in[17];
    const float* mb1     = (const float*)d_in[18];
    const float* mW2     = (const float*)d_in[19];
    const float* mb2     = (const float*)d_in[20];
    const float* mW3     = (const float*)d_in[21];
    const float* mb3     = (const float*)d_in[22];
    float* outp          = (float*)d_out;

    char* w = (char*)d_ws;
    auto alloc = [&](size_t bytes) -> void* {
        void* p = (void*)w;
        w += (bytes + 255) & ~(size_t)255;
        return p;
    };
    float*  hT    = (float*)alloc((size_t)80*NP_*4);           // 3.24 MB
    float*  Af    = (float*)alloc((size_t)N_*AW_*4);           // 16 MB
    __half* Bh    = (__half*)alloc((size_t)N_*BW_*2);          // 7.68 MB
    uint2*  agg2h = (uint2*)alloc((size_t)TF_*NP_*8);          // 30.3 MB
    float*  Yp0   = (float*)alloc((size_t)T_*YC_*NP_*4);       // 9.71 MB
    float*  Yp1   = (float*)alloc((size_t)T_*YC_*NP_*4);       // 9.71 MB
    float*  olinT = (float*)alloc((size_t)FIN_*NP_*4);         // 3.03 MB
    float*  ampv  = (float*)alloc(N_*4);
    float*  iampv = (float*)alloc(N_*4);
    float*  avglog= (float*)alloc(4);
    float*  tbl   = (float*)alloc(4*4*TF_*4);
    float*  eembw = (float*)alloc(4*4*FIN_*4);
    float*  Wcomb = (float*)alloc((size_t)4*T_*WK_*YC_*4);
    float*  Wpre80= (float*)alloc((size_t)4*10*80*80*4);       // 1.02 MB
    float*  Wlin80= (float*)alloc(4*FIN_*80*4);
    float*  bnsum = (float*)alloc(2*FIN_*4);
    float*  bnsq  = bnsum + FIN_;
    float*  pooled= (float*)alloc(G_*FIN_*4);
    int* deg_i   = (int*)alloc(N_*4);
    int* offs    = (int*)alloc((N_+1)*4);
    int* cursor  = (int*)alloc(N_*4);
    int* csr     = (int*)alloc(E_*4);

    hipMemsetAsync(deg_i, 0, N_*4, stream);
    hipMemsetAsync(cursor, 0, N_*4, stream);

    k_h0<<<(80*N_ + 255)/256, 256, 0, stream>>>(x, node_emb, hT);
    k_deg<<<(E_ + 255)/256, 256, 0, stream>>>(ei, deg_i);
    k_scan<<<1, 1024, 0, stream>>>(deg_i, offs, avglog);
    k_fill<<<(E_ + 255)/256, 256, 0, stream>>>(ei, eattr, offs, cursor, csr);
    k_amp<<<(N_ + 255)/256, 256, 0, stream>>>(deg_i, avglog, ampv, iampv);
    k_eemb<<<(4*4*FIN_ + 255)/256, 256, 0, stream>>>(edge_emb, We, be, eembw);
    k_tbl<<<(4*4*TF_ + 255)/256, 256, 0, stream>>>(eembw, Wpre, bpre, tbl);
    k_wcomb<<<(4*T_*WK_*YC_ + 255)/256, 256, 0, stream>>>(Wpost, Wcomb);
    k_wpre80<<<(4*10*80*80 + 255)/256, 256, 0, stream>>>(Wpre, Wpre80);
    k_wlin80<<<(4*FIN_*80 + 255)/256, 256, 0, stream>>>(Wlin, Wlin80);

    int nab = NP_/64;          // 158 M-tiles (k_A4)
    int npb = (N_ + 63)/64;    // 157 M-tiles (k_post6) / row-blocks (k_Y)
    for (int l = 0; l < 4; l++){
        hipMemsetAsync(bnsum, 0, 2*FIN_*4, stream);
        k_A4<<<dim3(nab, 10), 128, 0, stream>>>(hT, Wpre80 + (size_t)l*10*6400, Af, Bh);
        k_agg<<<N_, 128, 0, stream>>>(Af, Bh, offs, csr, tbl + (size_t)l*4*TF_, agg2h);
        k_post6<<<dim3(npb, T_, 2), 128, 0, stream>>>(hT, agg2h, Wcomb + (size_t)l*T_*WK_*YC_, Yp0, Yp1);
        k_Y<<<dim3(npb, 2), 64, 0, stream>>>(Yp0, Yp1, ampv, iampv, bpost + l*T_*FOUT_,
                                             Wlin80 + (size_t)l*FIN_*80, blin + l*FIN_,
                                             olinT, bnsum, bnsq);
        k_bn<<<(FIN_*N_ + 255)/256, 256, 0, stream>>>(olinT, bnsum, bnsq,
                                                      bn_gamma + l*FIN_, bn_beta + l*FIN_, uafp, hT);
    }

    k_pool2<<<G_, 256, 0, stream>>>(hT, batch, pooled);
    k_mlp<<<G_, 64, 0, stream>>>(pooled, mW1, mb1, mW2, mb2, mW3, mb3, uafp, outp);
}

// Round 13
// 833.859 us; speedup vs baseline: 1.0504x; 1.0504x over previous
//
#include <hip/hip_runtime.h>
#include <hip/hip_fp16.h>
#include <math.h>

// ---- problem constants ----
static constexpr int N_   = 10000;
static constexpr int E_   = 160000;
static constexpr int G_   = 64;
static constexpr int T_   = 5;
static constexpr int FIN_ = 75;
static constexpr int ED_  = 50;
static constexpr int FOUT_= 15;
static constexpr int TF_  = T_*FIN_;     // 375
static constexpr int AGGW_= 4*FIN_;      // 300
static constexpr int YC_  = 48;          // padded 45 -> 48 combined outputs
static constexpr int NP_  = 10112;       // padded node count = 158*64 (tile-exact)
static constexpr int AW_  = 400;         // Af row: 5 towers x 80 (f32)
static constexpr int BW_  = 384;         // Bh row: 5 towers x 76 + pad (fp16), 768 B
static constexpr int WK_  = 380;         // Wcomb K rows: 80 (h+pad) + 300 (agg fi-quad interleaved)

// ---- UAF ----
__device__ __forceinline__ float softplus_f(float x){
    return fmaxf(x, 0.f) + log1pf(expf(-fabsf(x)));
}
__device__ __forceinline__ float uaf_f(float v, const float* __restrict__ p){
    return softplus_f(p[0]*(v + p[1]) + p[2]*v*v) - softplus_f(p[3]*(v - p[1])) + p[4];
}
__device__ __forceinline__ unsigned pack2h(float a, float b){
    __half2 h = __floats2half2_rn(a, b);
    return *reinterpret_cast<unsigned*>(&h);
}

// ---- setup kernels ----
__global__ void k_h0(const int* __restrict__ x, const float* __restrict__ node_emb, float* __restrict__ hT){
    int i = blockIdx.x*blockDim.x + threadIdx.x;
    if (i >= 80*N_) return;
    int q = i / N_, n = i % N_;
    hT[(size_t)q*NP_ + n] = (q < FIN_) ? node_emb[x[n]*FIN_ + q] : 0.f;
}

__global__ void k_deg(const int* __restrict__ ei, int* __restrict__ deg_i){
    int e = blockIdx.x*blockDim.x + threadIdx.x;
    if (e >= E_) return;
    atomicAdd(&deg_i[ei[E_ + e]], 1);
}

__global__ void k_scan(const int* __restrict__ deg_i, int* __restrict__ offs, float* __restrict__ avglog){
    __shared__ int sd[1024];
    __shared__ float sf[1024];
    __shared__ int carry;
    if (threadIdx.x == 0) carry = 0;
    __syncthreads();
    float ls = 0.f;
    for (int base = 0; base < N_; base += 1024){
        int i = base + threadIdx.x;
        int v = (i < N_) ? deg_i[i] : 0;
        if (i < N_) ls += logf((float)v + 1.f);
        sd[threadIdx.x] = v;
        __syncthreads();
        for (int off = 1; off < 1024; off <<= 1){
            int t = (threadIdx.x >= off) ? sd[threadIdx.x - off] : 0;
            __syncthreads();
            sd[threadIdx.x] += t;
            __syncthreads();
        }
        if (i < N_) offs[i] = carry + sd[threadIdx.x] - v;
        __syncthreads();
        if (threadIdx.x == 0) carry += sd[1023];
        __syncthreads();
    }
    if (threadIdx.x == 0) offs[N_] = carry;
    sf[threadIdx.x] = ls;
    __syncthreads();
    for (int off = 512; off > 0; off >>= 1){
        if (threadIdx.x < off) sf[threadIdx.x] += sf[threadIdx.x + off];
        __syncthreads();
    }
    if (threadIdx.x == 0) avglog[0] = sf[0] / (float)N_;
}

__global__ void k_fill(const int* __restrict__ ei, const int* __restrict__ eattr,
                       const int* __restrict__ offs, int* __restrict__ cursor, int* __restrict__ csr){
    int e = blockIdx.x*blockDim.x + threadIdx.x;
    if (e >= E_) return;
    int d = ei[E_ + e];
    int pos = offs[d] + atomicAdd(&cursor[d], 1);
    csr[pos] = ei[e] | (eattr[e] << 16);
}

__global__ void k_amp(const int* __restrict__ deg_i, const float* __restrict__ avglog,
                      float* __restrict__ ampv, float* __restrict__ iampv){
    int n = blockIdx.x*blockDim.x + threadIdx.x;
    if (n >= N_) return;
    float dm = fmaxf((float)deg_i[n], 1.f);
    float a = logf(dm + 1.f) / avglog[0];
    ampv[n] = a;
    iampv[n] = 1.f / a;
}

__global__ void k_eemb(const float* __restrict__ edge_emb, const float* __restrict__ We,
                       const float* __restrict__ be, float* __restrict__ eembw){
    int i = blockIdx.x*blockDim.x + threadIdx.x;
    if (i >= 4*4*FIN_) return;
    int c = i % FIN_;
    int a = (i / FIN_) % 4;
    int l = i / (4*FIN_);
    float s = be[l*FIN_ + c];
    for (int k = 0; k < ED_; k++) s = fmaf(edge_emb[a*ED_ + k], We[(l*ED_ + k)*FIN_ + c], s);
    eembw[i] = s;
}

__global__ void k_tbl(const float* __restrict__ eembw, const float* __restrict__ Wpre,
                      const float* __restrict__ bpre, float* __restrict__ tbl){
    int i = blockIdx.x*blockDim.x + threadIdx.x;
    if (i >= 4*4*TF_) return;
    int f = i % FIN_;
    int t = (i / FIN_) % T_;
    int a = (i / TF_) % 4;
    int l = i / (4*TF_);
    float s = bpre[(l*T_ + t)*FIN_ + f];
    const float* em = eembw + (l*4 + a)*FIN_;
    const float* W3 = Wpre + ((size_t)(l*T_ + t)*225 + 2*FIN_)*FIN_;
    for (int c = 0; c < FIN_; c++) s = fmaf(em[c], W3[c*FIN_ + f], s);
    tbl[i] = s;
}

// Wcomb[l,t,c,j]: WK_=380 x 48 per (l,t). K rows: 0..74 h, 75..79 zero pad,
// c>=80: r=c-80, fi=r>>2, kind=r&3 -> src agg row kind*75+fi (matches fp16 quad order).
__global__ void k_wcomb(const float* __restrict__ Wpost, float* __restrict__ Wcomb){
    int i = blockIdx.x*blockDim.x + threadIdx.x;
    if (i >= 4*T_*WK_*YC_) return;
    int j = i % YC_;
    int c = (i / YC_) % WK_;
    int t = (i / (YC_*WK_)) % T_;
    int l = i / (YC_*WK_*T_);
    float v = 0.f;
    if (j < 45){
        int blk = j / 15, fo = j % 15;
        const float* Wp = Wpost + (size_t)(l*T_ + t)*975*15;
        if (c < FIN_){ if (blk == 0) v = Wp[c*15 + fo]; }
        else if (c >= 80){
            int r = c - 80;
            int fi = r >> 2, kind = r & 3;
            v = Wp[(FIN_ + blk*AGGW_ + kind*FIN_ + fi)*15 + fo];
        }
    }
    Wcomb[i] = v;
}

// zero-padded Wpre blocks: Wpre80[l*10+chunk][80][80], chunk=t*2+half
__global__ void k_wpre80(const float* __restrict__ Wpre, float* __restrict__ Wpre80){
    int i = blockIdx.x*blockDim.x + threadIdx.x;
    if (i >= 4*10*80*80) return;
    int c = i % 80;
    int r = (i / 80) % 80;
    int chunk = (i / 6400) % 10;
    int l = i / 64000;
    int t = chunk >> 1, half = chunk & 1;
    float v = 0.f;
    if (r < FIN_ && c < FIN_)
        v = Wpre[((size_t)(l*T_ + t)*225 + half*FIN_ + r)*FIN_ + c];
    Wpre80[i] = v;
}

// zero-padded Wlin: [l][75][80]
__global__ void k_wlin80(const float* __restrict__ Wlin, float* __restrict__ Wlin80){
    int i = blockIdx.x*blockDim.x + threadIdx.x;
    if (i >= 4*FIN_*80) return;
    int q = i % 80;
    int p = (i / 80) % FIN_;
    int l = i / (80*FIN_);
    Wlin80[i] = (q < FIN_) ? Wlin[(l*FIN_ + p)*FIN_ + q] : 0.f;
}

// ---- per-layer kernels ----
// k_A5: M-tile 64, 128 threads, K=80 in 4 chunks of 20.
// Full W chunk (80x80) staged once in LDS; Act double-buffered via global_load_lds
// (zero-VGPR async staging). Out[64][81] overlays dead W region for coalesced stores.
__global__ void __launch_bounds__(128) k_A5(const float* __restrict__ hT, const float* __restrict__ Wpre80_l,
                                            float* __restrict__ Af, __half* __restrict__ Bh){
    __shared__ float smem[8960];      // 35.84 KB: W [0..6400), Act dbuf [6400..8960)
    float* Wt   = smem;
    float* ActB = smem + 6400;
    int chunkid = blockIdx.y;
    int t = chunkid >> 1, half = chunkid & 1;
    const float* __restrict__ Wl = Wpre80_l + (size_t)chunkid*6400;
    int n0 = blockIdx.x * 64;
    int tid = threadIdx.x;
    int tn = tid & 15, tj = tid >> 4;
    int wv = tid >> 6, ln = tid & 63;

    // prologue: stage full W (6400 floats) + Act chunk 0 (20 rows x 64)
    for (int i = tid; i < 1600; i += 128)
        *(float4*)(&Wt[i*4]) = *(const float4*)(Wl + i*4);
    for (int i = tid; i < 320; i += 128){
        int r = i >> 4, c4 = i & 15;
        *(float4*)(&ActB[r*64 + c4*4]) = *(const float4*)(hT + (size_t)r*NP_ + n0 + c4*4);
    }
    __syncthreads();

    float acc[4][10];
    #pragma unroll
    for (int m = 0; m < 4; m++)
        #pragma unroll
        for (int j = 0; j < 10; j++) acc[m][j] = 0.f;

    #pragma unroll 1
    for (int ch = 0; ch < 4; ch++){
        int buf = ch & 1;
        // async-prefetch Act chunk ch+1 into other buffer (no VGPR round-trip)
        if (ch < 3){
            const float* srcb = hT + (size_t)((ch+1)*20)*NP_ + n0;
            float* dstb = ActB + (buf ^ 1)*1280;
            int r0 = (ln >> 4), c = (ln & 15)*4;
            if (wv == 0){
                #pragma unroll
                for (int s = 0; s < 3; s++)
                    __builtin_amdgcn_global_load_lds(
                        (const __attribute__((address_space(1))) unsigned*)(srcb + (size_t)(s*4 + r0)*NP_ + c),
                        (__attribute__((address_space(3))) unsigned*)(dstb + s*256),
                        16, 0, 0);
            } else {
                #pragma unroll
                for (int s = 3; s < 5; s++)
                    __builtin_amdgcn_global_load_lds(
                        (const __attribute__((address_space(1))) unsigned*)(srcb + (size_t)(s*4 + r0)*NP_ + c),
                        (__attribute__((address_space(3))) unsigned*)(dstb + s*256),
                        16, 0, 0);
            }
        }
        // compute current chunk
        const float* A = ActB + buf*1280;
        const float* Wc = Wt + ch*20*80;
        #pragma unroll
        for (int k = 0; k < 20; k++){
            float4 av = *(const float4*)(A + (k<<6) + (tn<<2));
            const float2* wr = (const float2*)(Wc + k*80 + tj*10);
            float wvv[10];
            #pragma unroll
            for (int j2 = 0; j2 < 5; j2++){ float2 w2 = wr[j2]; wvv[2*j2] = w2.x; wvv[2*j2+1] = w2.y; }
            #pragma unroll
            for (int j = 0; j < 10; j++){
                acc[0][j] = fmaf(av.x, wvv[j], acc[0][j]);
                acc[1][j] = fmaf(av.y, wvv[j], acc[1][j]);
                acc[2][j] = fmaf(av.z, wvv[j], acc[2][j]);
                acc[3][j] = fmaf(av.w, wvv[j], acc[3][j]);
            }
        }
        __syncthreads();   // drains global_load_lds (vmcnt) + protects buffer swap
    }

    // Out[64][81] overlays W region (dead after last chunk's barrier)
    float* Out = smem;
    #pragma unroll
    for (int m = 0; m < 4; m++)
        #pragma unroll
        for (int j = 0; j < 10; j++)
            Out[(tn*4 + m)*81 + tj*10 + j] = acc[m][j];
    __syncthreads();
    if (half == 0){
        for (int i = tid; i < 64*20; i += 128){
            int node = i / 20, q4 = i % 20;
            int gn = n0 + node;
            if (gn < N_){
                const float* src = Out + node*81 + q4*4;
                *(float4*)(Af + (size_t)gn*AW_ + t*80 + q4*4) = make_float4(src[0], src[1], src[2], src[3]);
            }
        }
    } else {
        for (int i = tid; i < 64*38; i += 128){
            int node = i / 38, q = i % 38;
            int gn = n0 + node;
            if (gn < N_){
                const float* src = Out + node*81 + 2*q;
                *(unsigned*)((__half*)Bh + (size_t)gn*BW_ + t*76 + 2*q) = pack2h(src[0], src[1]);
            }
        }
    }
}

// per-node CSR aggregation -> packed fp16 quad {mean,mn,mx,sd} at agg2h[(t*75+fi)*NP_ + n]
__global__ void __launch_bounds__(128) k_agg(const float* __restrict__ Af, const __half* __restrict__ Bh,
                                             const int* __restrict__ offs, const int* __restrict__ csr,
                                             const float* __restrict__ tbl_l, uint2* __restrict__ agg2h){
    __shared__ float tl[4*TF_];
    int bid = blockIdx.x;
    int n = (bid & 7)*1250 + (bid >> 3);   // XCD swizzle
    for (int idx = threadIdx.x; idx < 4*TF_; idx += 128) tl[idx] = tbl_l[idx];
    __syncthreads();
    int s = offs[n], e_end = offs[n+1];
    int f0 = threadIdx.x;
    int f1 = threadIdx.x + 128;
    int f2r = threadIdx.x + 256;
    int f2 = (f2r < TF_) ? f2r : 0;
    int aoA0 = (f0/FIN_)*80 + f0%FIN_;
    int aoA1 = (f1/FIN_)*80 + f1%FIN_;
    int aoA2 = (f2/FIN_)*80 + f2%FIN_;
    int aoB0 = (f0/FIN_)*76 + f0%FIN_;
    int aoB1 = (f1/FIN_)*76 + f1%FIN_;
    int aoB2 = (f2/FIN_)*76 + f2%FIN_;
    const float* An = Af + (size_t)n*AW_;
    float a0 = An[aoA0], a1 = An[aoA1], a2 = An[aoA2];
    float s0=0.f,s1=0.f,s2=0.f, q0=0.f,q1=0.f,q2=0.f;
    float mn0=INFINITY,mn1=INFINITY,mn2=INFINITY;
    float mx0=-INFINITY,mx1=-INFINITY,mx2=-INFINITY;
    int e = s;
    for (; e + 3 < e_end; e += 4){
        float b0[4], b1[4], b2[4];
        const float* tt[4];
        #pragma unroll
        for (int u = 0; u < 4; u++){
            int pk = csr[e + u];
            const __half* B = Bh + (size_t)(pk & 0xFFFF)*BW_;
            tt[u] = tl + (pk >> 16)*TF_;
            b0[u] = __half2float(B[aoB0]);
            b1[u] = __half2float(B[aoB1]);
            b2[u] = __half2float(B[aoB2]);
        }
        #pragma unroll
        for (int u = 0; u < 4; u++){
            float m0 = a0 + b0[u] + tt[u][f0];
            float m1 = a1 + b1[u] + tt[u][f1];
            float m2 = a2 + b2[u] + tt[u][f2];
            s0 += m0; s1 += m1; s2 += m2;
            q0 = fmaf(m0,m0,q0); q1 = fmaf(m1,m1,q1); q2 = fmaf(m2,m2,q2);
            mn0 = fminf(mn0,m0); mx0 = fmaxf(mx0,m0);
            mn1 = fminf(mn1,m1); mx1 = fmaxf(mx1,m1);
            mn2 = fminf(mn2,m2); mx2 = fmaxf(mx2,m2);
        }
    }
    for (; e < e_end; e++){
        int pk = csr[e];
        const __half* B = Bh + (size_t)(pk & 0xFFFF)*BW_;
        const float* t0 = tl + (pk >> 16)*TF_;
        float m0 = a0 + __half2float(B[aoB0]) + t0[f0];
        float m1 = a1 + __half2float(B[aoB1]) + t0[f1];
        float m2 = a2 + __half2float(B[aoB2]) + t0[f2];
        s0 += m0; q0 = fmaf(m0,m0,q0); mn0 = fminf(mn0,m0); mx0 = fmaxf(mx0,m0);
        s1 += m1; q1 = fmaf(m1,m1,q1); mn1 = fminf(mn1,m1); mx1 = fmaxf(mx1,m1);
        s2 += m2; q2 = fmaf(m2,m2,q2); mn2 = fminf(mn2,m2); mx2 = fmaxf(mx2,m2);
    }
    float deg = (float)(e_end - s);
    float dc = fmaxf(deg, 1.f);
    float inv = 1.f / dc;
    bool empty = (deg == 0.f);
    {
        float mean = s0*inv;
        float sd = sqrtf(fmaxf(q0*inv - mean*mean, 0.f) + 1e-5f);
        int t = f0/FIN_, fi = f0%FIN_;
        uint2 o; o.x = pack2h(mean, empty?0.f:mn0); o.y = pack2h(empty?0.f:mx0, sd);
        agg2h[(size_t)(t*FIN_+fi)*NP_ + n] = o;
    }
    {
        float mean = s1*inv;
        float sd = sqrtf(fmaxf(q1*inv - mean*mean, 0.f) + 1e-5f);
        int t = f1/FIN_, fi = f1%FIN_;
        uint2 o; o.x = pack2h(mean, empty?0.f:mn1); o.y = pack2h(empty?0.f:mx1, sd);
        agg2h[(size_t)(t*FIN_+fi)*NP_ + n] = o;
    }
    if (f2r < TF_){
        float mean = s2*inv;
        float sd = sqrtf(fmaxf(q2*inv - mean*mean, 0.f) + 1e-5f);
        int t = f2r/FIN_, fi = f2r%FIN_;
        uint2 o; o.x = pack2h(mean, empty?0.f:mn2); o.y = pack2h(empty?0.f:mx2, sd);
        agg2h[(size_t)(t*FIN_+fi)*NP_ + n] = o;
    }
}

__device__ __forceinline__ void unp4_64(float* Ad, int i, uint2 u){
    int fq = i >> 6, n = i & 63;
    __half2 lo = *reinterpret_cast<__half2*>(&u.x);
    __half2 hi = *reinterpret_cast<__half2*>(&u.y);
    Ad[(fq*4+0)*64 + n] = __low2float(lo);
    Ad[(fq*4+1)*64 + n] = __high2float(lo);
    Ad[(fq*4+2)*64 + n] = __low2float(hi);
    Ad[(fq*4+3)*64 + n] = __high2float(hi);
}

// K-split double-buffered GEMM. M-tile 64, 128 threads (2 waves), grid (157, T, 2).
__global__ void __launch_bounds__(128) k_post6(const float* __restrict__ hT, const uint2* __restrict__ agg2h,
                                               const float* __restrict__ Wcomb_l,
                                               float* __restrict__ Yp0, float* __restrict__ Yp1){
    __shared__ float Act[2][20*64];
    __shared__ float Wt[2][20*YC_];
    int t = blockIdx.y;
    int kz = blockIdx.z;
    int c0 = kz ? 9 : 0;
    int c1 = kz ? 19 : 9;
    float* __restrict__ Yp = kz ? Yp1 : Yp0;
    int n0 = blockIdx.x * 64;
    int tid = threadIdx.x;
    int tn = tid & 15, tj = tid >> 4;
    const float* __restrict__ Wl = Wcomb_l + (size_t)t*WK_*YC_;
    const uint2* __restrict__ agt = agg2h + (size_t)t*FIN_*NP_;

    if (c0 < 4){
        const float* sp = hT + (size_t)(c0*20)*NP_ + n0;
        for (int i = tid; i < 320; i += 128){
            int r = i >> 4, c4 = i & 15;
            *(float4*)(&Act[0][r*64 + c4*4]) = *(const float4*)(sp + (size_t)r*NP_ + c4*4);
        }
    } else {
        const uint2* sp = agt + (size_t)((c0 - 4)*5)*NP_ + n0;
        for (int i = tid; i < 320; i += 128)
            unp4_64(Act[0], i, sp[(size_t)(i >> 6)*NP_ + (i & 63)]);
    }
    for (int i = tid; i < 240; i += 128){
        int r = i / 12, c4 = i % 12;
        *(float4*)(&Wt[0][r*YC_ + c4*4]) = *(const float4*)(Wl + (size_t)(c0*20 + r)*YC_ + c4*4);
    }
    __syncthreads();

    float acc[4][6];
    #pragma unroll
    for (int m = 0; m < 4; m++)
        #pragma unroll
        for (int j = 0; j < 6; j++) acc[m][j] = 0.f;

    float4 ph0, ph1, ph2, pw0, pw1;
    uint2  pb0, pb1, pb2;
    #pragma unroll 1
    for (int ch = c0; ch < c1; ch++){
        int buf = (ch - c0) & 1;
        int ch1 = ch + 1;
        bool have = (ch1 < c1);
        bool nh = (ch1 < 4);
        if (have){
            if (nh){
                const float* sp = hT + (size_t)(ch1*20)*NP_ + n0;
                { int i0 = tid;       ph0 = *(const float4*)(sp + (size_t)(i0 >> 4)*NP_ + (i0 & 15)*4); }
                { int i1 = tid + 128; ph1 = *(const float4*)(sp + (size_t)(i1 >> 4)*NP_ + (i1 & 15)*4); }
                if (tid < 64){ int i2 = tid + 256; ph2 = *(const float4*)(sp + (size_t)(i2 >> 4)*NP_ + (i2 & 15)*4); }
            } else {
                const uint2* sp = agt + (size_t)((ch1 - 4)*5)*NP_ + n0;
                { int i0 = tid;       pb0 = sp[(size_t)(i0 >> 6)*NP_ + (i0 & 63)]; }
                { int i1 = tid + 128; pb1 = sp[(size_t)(i1 >> 6)*NP_ + (i1 & 63)]; }
                if (tid < 64){ int i2 = tid + 256; pb2 = sp[(size_t)(i2 >> 6)*NP_ + (i2 & 63)]; }
            }
            { int i = tid; int r = i / 12, c4 = i % 12;
              pw0 = *(const float4*)(Wl + (size_t)(ch1*20 + r)*YC_ + c4*4); }
            if (tid < 112){ int i = tid + 128; int r = i / 12, c4 = i % 12;
              pw1 = *(const float4*)(Wl + (size_t)(ch1*20 + r)*YC_ + c4*4); }
        }
        const float* A = Act[buf];
        const float* Wb = Wt[buf];
        #pragma unroll
        for (int k = 0; k < 20; k++){
            float4 av = *(const float4*)(A + (k<<6) + (tn<<2));
            const float* wr = Wb + k*YC_ + tj*6;
            #pragma unroll
            for (int j = 0; j < 6; j++){
                float wv = wr[j];
                acc[0][j] = fmaf(av.x, wv, acc[0][j]);
                acc[1][j] = fmaf(av.y, wv, acc[1][j]);
                acc[2][j] = fmaf(av.z, wv, acc[2][j]);
                acc[3][j] = fmaf(av.w, wv, acc[3][j]);
            }
        }
        if (have){
            float* Ad = Act[buf ^ 1];
            float* Wd = Wt[buf ^ 1];
            if (nh){
                { int i0 = tid;       *(float4*)(&Ad[(i0 >> 4)*64 + (i0 & 15)*4]) = ph0; }
                { int i1 = tid + 128; *(float4*)(&Ad[(i1 >> 4)*64 + (i1 & 15)*4]) = ph1; }
                if (tid < 64){ int i2 = tid + 256; *(float4*)(&Ad[(i2 >> 4)*64 + (i2 & 15)*4]) = ph2; }
            } else {
                unp4_64(Ad, tid, pb0);
                unp4_64(Ad, tid + 128, pb1);
                if (tid < 64) unp4_64(Ad, tid + 256, pb2);
            }
            { int i = tid; int r = i / 12, c4 = i % 12; *(float4*)(&Wd[r*YC_ + c4*4]) = pw0; }
            if (tid < 112){ int i = tid + 128; int r = i / 12, c4 = i % 12; *(float4*)(&Wd[r*YC_ + c4*4]) = pw1; }
            __syncthreads();
        }
    }
    int nodeb = n0 + tn*4;
    #pragma unroll
    for (int j = 0; j < 6; j++){
        int col = t*YC_ + tj*6 + j;
        float4 v = make_float4(acc[0][j], acc[1][j], acc[2][j], acc[3][j]);
        if (nodeb + 3 < N_){
            *(float4*)(Yp + (size_t)col*NP_ + nodeb) = v;
        } else {
            #pragma unroll
            for (int m = 0; m < 4; m++)
                if (nodeb + m < N_) Yp[(size_t)col*NP_ + nodeb + m] = (&v.x)[m];
        }
    }
}

// combine (Yp0+Yp1) + Wlin + BN stats; q-range split over blockIdx.y
__global__ void __launch_bounds__(64) k_Y(const float* __restrict__ Yp0, const float* __restrict__ Yp1,
                                          const float* __restrict__ ampv,
                                          const float* __restrict__ iampv, const float* __restrict__ bpost_l,
                                          const float* __restrict__ Wlin80_l, const float* __restrict__ blin_l,
                                          float* __restrict__ olinT, float* __restrict__ bnsum, float* __restrict__ bnsq){
    __shared__ float st[64*77];
    int qbase = blockIdx.y * 40;
    int qcnt  = blockIdx.y ? 35 : 40;
    int n = blockIdx.x*64 + threadIdx.x;
    int nn = (n < N_) ? n : N_-1;
    bool valid = (n < N_);
    float amp = ampv[nn], iamp = iampv[nn];
    #pragma unroll 1
    for (int t = 0; t < T_; t++){
        #pragma unroll
        for (int fo = 0; fo < FOUT_; fo++){
            size_t b0 = (size_t)(t*YC_ + fo)*NP_ + nn;
            size_t b1 = (size_t)(t*YC_ + 15 + fo)*NP_ + nn;
            size_t b2 = (size_t)(t*YC_ + 30 + fo)*NP_ + nn;
            float v = (Yp0[b0] + Yp1[b0])
                    + amp  * (Yp0[b1] + Yp1[b1])
                    + iamp * (Yp0[b2] + Yp1[b2])
                    + bpost_l[t*FOUT_ + fo];
            st[threadIdx.x*77 + t*FOUT_ + fo] = v;
        }
    }
    __syncthreads();
    float acc[40];
    #pragma unroll
    for (int k = 0; k < 40; k++) acc[k] = (qbase + k < FIN_) ? blin_l[qbase + k] : 0.f;
    #pragma unroll 1
    for (int p = 0; p < FIN_; p++){
        float yv = st[threadIdx.x*77 + p];
        const float* Wp = Wlin80_l + p*80 + qbase;
        #pragma unroll
        for (int k = 0; k < 40; k++) acc[k] = fmaf(yv, Wp[k], acc[k]);
    }
    if (valid){
        #pragma unroll
        for (int k = 0; k < 40; k++){
            int q = qbase + k;
            if (q < FIN_) olinT[(size_t)q*NP_ + n] = acc[k];
        }
    }
    __syncthreads();
    #pragma unroll
    for (int k = 0; k < 40; k++) st[threadIdx.x*77 + k] = valid ? acc[k] : 0.f;
    __syncthreads();
    for (int qq = threadIdx.x; qq < qcnt; qq += 64){
        float s = 0.f, s2 = 0.f;
        #pragma unroll 4
        for (int m = 0; m < 64; m++){ float v = st[m*77 + qq]; s += v; s2 = fmaf(v, v, s2); }
        atomicAdd(&bnsum[qbase + qq], s);
        atomicAdd(&bnsq[qbase + qq], s2);
    }
}

__global__ void k_bn(const float* __restrict__ olinT, const float* __restrict__ bnsum, const float* __restrict__ bnsq,
                     const float* __restrict__ gamma_l, const float* __restrict__ beta_l,
                     const float* __restrict__ uafp, float* __restrict__ hT){
    int i = blockIdx.x*blockDim.x + threadIdx.x;
    if (i >= FIN_*N_) return;
    int q = i / N_, n = i % N_;
    float mu = bnsum[q] * (1.f/(float)N_);
    float var = bnsq[q] * (1.f/(float)N_) - mu*mu;
    float xh = (olinT[(size_t)q*NP_ + n] - mu) * rsqrtf(var + 1e-5f) * gamma_l[q] + beta_l[q];
    hT[(size_t)q*NP_ + n] = uaf_f(xh, uafp);
}

// ---- pooling + MLP ----
__global__ void __launch_bounds__(256) k_pool2(const float* __restrict__ hT, const int* __restrict__ batch,
                                               float* __restrict__ pooled){
    __shared__ int sb[2];
    int g = blockIdx.x;
    if (threadIdx.x < 2){
        int key = g + threadIdx.x;
        int lo = 0, hi = N_;
        while (lo < hi){ int mid = (lo + hi) >> 1; if (batch[mid] < key) lo = mid + 1; else hi = mid; }
        sb[threadIdx.x] = lo;
    }
    __syncthreads();
    int s = sb[0], e = sb[1];
    int wave = threadIdx.x >> 6, lane = threadIdx.x & 63;
    for (int q = wave; q < FIN_; q += 4){
        float sum = 0.f;
        for (int n = s + lane; n < e; n += 64) sum += hT[(size_t)q*NP_ + n];
        #pragma unroll
        for (int off = 32; off > 0; off >>= 1) sum += __shfl_down(sum, off);
        if (lane == 0) pooled[g*FIN_ + q] = sum;
    }
}

__global__ void __launch_bounds__(64) k_mlp(const float* __restrict__ pooled,
        const float* __restrict__ mW1, const float* __restrict__ mb1,
        const float* __restrict__ mW2, const float* __restrict__ mb2,
        const float* __restrict__ mW3, const float* __restrict__ mb3,
        const float* __restrict__ uafp, float* __restrict__ outp){
    __shared__ float pr[FIN_];
    __shared__ float z1[50];
    __shared__ float z2[25];
    int g = blockIdx.x;
    for (int c = threadIdx.x; c < FIN_; c += 64) pr[c] = pooled[g*FIN_ + c];
    __syncthreads();
    if (threadIdx.x < 50){
        float s = mb1[threadIdx.x];
        for (int c = 0; c < FIN_; c++) s = fmaf(pr[c], mW1[c*50 + threadIdx.x], s);
        z1[threadIdx.x] = uaf_f(s, uafp);
    }
    __syncthreads();
    if (threadIdx.x < 25){
        float s = mb2[threadIdx.x];
        for (int c = 0; c < 50; c++) s = fmaf(z1[c], mW2[c*25 + threadIdx.x], s);
        z2[threadIdx.x] = uaf_f(s, uafp);
    }
    __syncthreads();
    if (threadIdx.x == 0){
        float s = mb3[0];
        for (int c = 0; c < 25; c++) s = fmaf(z2[c], mW3[c], s);
        outp[g] = s;
    }
}

extern "C" void kernel_launch(void* const* d_in, const int* in_sizes, int n_in,
                              void* d_out, int out_size, void* d_ws, size_t ws_size,
                              hipStream_t stream) {
    const int* x         = (const int*)d_in[0];
    const int* ei        = (const int*)d_in[1];
    const int* eattr     = (const int*)d_in[2];
    const int* batch     = (const int*)d_in[3];
    const float* node_emb= (const float*)d_in[4];
    const float* edge_emb= (const float*)d_in[5];
    const float* We      = (const float*)d_in[6];
    const float* be      = (const float*)d_in[7];
    const float* Wpre    = (const float*)d_in[8];
    const float* bpre    = (const float*)d_in[9];
    const float* Wpost   = (const float*)d_in[10];
    const float* bpost   = (const float*)d_in[11];
    const float* Wlin    = (const float*)d_in[12];
    const float* blin    = (const float*)d_in[13];
    const float* bn_gamma= (const float*)d_in[14];
    const float* bn_beta = (const float*)d_in[15];
    const float* uafp    = (const float*)d_in[16];
    const float* mW1     = (const float*)d_in[17];
    const float* mb1     = (const float*)d_in[18];
    const float* mW2     = (const float*)d_in[19];
    const float* mb2     = (const float*)d_in[20];
    const float* mW3     = (const float*)d_in[21];
    const float* mb3     = (const float*)d_in[22];
    float* outp          = (float*)d_out;

    char* w = (char*)d_ws;
    auto alloc = [&](size_t bytes) -> void* {
        void* p = (void*)w;
        w += (bytes + 255) & ~(size_t)255;
        return p;
    };
    float*  hT    = (float*)alloc((size_t)80*NP_*4);           // 3.24 MB
    float*  Af    = (float*)alloc((size_t)N_*AW_*4);           // 16 MB
    __half* Bh    = (__half*)alloc((size_t)N_*BW_*2);          // 7.68 MB
    uint2*  agg2h = (uint2*)alloc((size_t)TF_*NP_*8);          // 30.3 MB
    float*  Yp0   = (float*)alloc((size_t)T_*YC_*NP_*4);       // 9.71 MB
    float*  Yp1   = (float*)alloc((size_t)T_*YC_*NP_*4);       // 9.71 MB
    float*  olinT = (float*)alloc((size_t)FIN_*NP_*4);         // 3.03 MB
    float*  ampv  = (float*)alloc(N_*4);
    float*  iampv = (float*)alloc(N_*4);
    float*  avglog= (float*)alloc(4);
    float*  tbl   = (float*)alloc(4*4*TF_*4);
    float*  eembw = (float*)alloc(4*4*FIN_*4);
    float*  Wcomb = (float*)alloc((size_t)4*T_*WK_*YC_*4);
    float*  Wpre80= (float*)alloc((size_t)4*10*80*80*4);       // 1.02 MB
    float*  Wlin80= (float*)alloc(4*FIN_*80*4);
    float*  bnsum = (float*)alloc(2*FIN_*4);
    float*  bnsq  = bnsum + FIN_;
    float*  pooled= (float*)alloc(G_*FIN_*4);
    int* deg_i   = (int*)alloc(N_*4);
    int* offs    = (int*)alloc((N_+1)*4);
    int* cursor  = (int*)alloc(N_*4);
    int* csr     = (int*)alloc(E_*4);

    hipMemsetAsync(deg_i, 0, N_*4, stream);
    hipMemsetAsync(cursor, 0, N_*4, stream);

    k_h0<<<(80*N_ + 255)/256, 256, 0, stream>>>(x, node_emb, hT);
    k_deg<<<(E_ + 255)/256, 256, 0, stream>>>(ei, deg_i);
    k_scan<<<1, 1024, 0, stream>>>(deg_i, offs, avglog);
    k_fill<<<(E_ + 255)/256, 256, 0, stream>>>(ei, eattr, offs, cursor, csr);
    k_amp<<<(N_ + 255)/256, 256, 0, stream>>>(deg_i, avglog, ampv, iampv);
    k_eemb<<<(4*4*FIN_ + 255)/256, 256, 0, stream>>>(edge_emb, We, be, eembw);
    k_tbl<<<(4*4*TF_ + 255)/256, 256, 0, stream>>>(eembw, Wpre, bpre, tbl);
    k_wcomb<<<(4*T_*WK_*YC_ + 255)/256, 256, 0, stream>>>(Wpost, Wcomb);
    k_wpre80<<<(4*10*80*80 + 255)/256, 256, 0, stream>>>(Wpre, Wpre80);
    k_wlin80<<<(4*FIN_*80 + 255)/256, 256, 0, stream>>>(Wlin, Wlin80);

    int nab = NP_/64;          // 158 M-tiles (k_A5)
    int npb = (N_ + 63)/64;    // 157 M-tiles (k_post6) / row-blocks (k_Y)
    for (int l = 0; l < 4; l++){
        hipMemsetAsync(bnsum, 0, 2*FIN_*4, stream);
        k_A5<<<dim3(nab, 10), 128, 0, stream>>>(hT, Wpre80 + (size_t)l*10*6400, Af, Bh);
        k_agg<<<N_, 128, 0, stream>>>(Af, Bh, offs, csr, tbl + (size_t)l*4*TF_, agg2h);
        k_post6<<<dim3(npb, T_, 2), 128, 0, stream>>>(hT, agg2h, Wcomb + (size_t)l*T_*WK_*YC_, Yp0, Yp1);
        k_Y<<<dim3(npb, 2), 64, 0, stream>>>(Yp0, Yp1, ampv, iampv, bpost + l*T_*FOUT_,
                                             Wlin80 + (size_t)l*FIN_*80, blin + l*FIN_,
                                             olinT, bnsum, bnsq);
        k_bn<<<(FIN_*N_ + 255)/256, 256, 0, stream>>>(olinT, bnsum, bnsq,
                                                      bn_gamma + l*FIN_, bn_beta + l*FIN_, uafp, hT);
    }

    k_pool2<<<G_, 256, 0, stream>>>(hT, batch, pooled);
    k_mlp<<<G_, 64, 0, stream>>>(pooled, mW1, mb1, mW2, mb2, mW3, mb3, uafp, outp);
}